// Round 11
// baseline (278.106 us; speedup 1.0000x reference)
//
#include <hip/hip_runtime.h>
#include <hip/hip_bf16.h>
#include <stdint.h>

#define NWIN 1728
#define SPD  110592   // 48*48*48

typedef __attribute__((ext_vector_type(8)))  short  short8;
typedef __attribute__((ext_vector_type(4)))  short  short4v;
typedef __attribute__((ext_vector_type(4)))  float  f32x4;
typedef __attribute__((ext_vector_type(16))) float  f32x16;

// LDS row strides (in shorts). All multiples of 8 (16-B row alignment for b128).
#define SRS 136   // x / ao tile rows
#define SQS 24    // sq/sk rows: 16-B aligned rows, writes 16 banks 2-way
#define SVS 72    // sv / P~ rows (36 words: b16 stores hit 32 banks 2-way = free)

// zero-cost compiler reorder fence (no instruction emitted)
#define CFENCE() asm volatile("" ::: "memory")
// hard LDS drain (proven R2 ordering for LDS RAW visibility)
#define LFENCE() asm volatile("s_waitcnt lgkmcnt(0)" ::: "memory")

// NOTE: v_cvt_pk_bf16_f32 inline asm is PERMANENTLY BANNED — R10 isolated it as
// the R1/R3 correctness bug (R9-base + cvtpk alone -> NaN). Software f2bf only.
__device__ __forceinline__ short f2bf(float f) {
  uint32_t u = __builtin_bit_cast(uint32_t, f);
  u += 0x7FFFu + ((u >> 16) & 1u);          // RTNE
  return (short)(u >> 16);
}

// ---- one-time (per launch) fp32 -> bf16 weight conversion into workspace ----
__global__ void cvt_weights_kernel(const float* __restrict__ wqkv,
                                   const float* __restrict__ wout,
                                   short* __restrict__ wq_bf,
                                   short* __restrict__ wo_bf) {
  int i = blockIdx.x * 256 + threadIdx.x;   // grid = 192*256 = 49152 exactly
  wq_bf[i] = f2bf(wqkv[i]);
  if (i < 128 * 128) wo_bf[i] = f2bf(wout[i]);
}

// ---- fused: x -> qkv -> windowed attention -> out projection ----
// Base = R9 (harness-proven 135us). Single structural change this round:
// head-1's QKV is issued BEFORE head-0's attention (after h0's q/k/v frags are
// hoisted to registers, sq/sk/sv are dead for h0 -> h1 may overwrite them;
// same-wave in-order DS + same-array aliasing, the pattern proven in R6-R8).
// This gives the scheduler ~48 independent MFMAs + loads to fill h0's
// exp/LDS-drain stall slots. Numerics byte-identical to R9.
__global__ __launch_bounds__(256, 3)
void win_attn_kernel(const float* __restrict__ x,
                     const short* __restrict__ wqkv_bf,
                     const short* __restrict__ wout_bf,
                     const float* __restrict__ bout,
                     float* __restrict__ out) {
  // LDS: sU 18432 + sq 12288 + sk 12288 + sv 9216 = 52224 B (3 blocks/CU)
  __shared__ __align__(16) short sU[4 * 32 * SVS];   // xs (17408 used) / P~ / ao
  __shared__ __align__(16) short sq[4][64 * SQS];    // per-wave q  [t][hd]
  __shared__ __align__(16) short sk[4][64 * SQS];    // per-wave k  [t][hd]
  __shared__ __align__(16) short sv[4][16 * SVS];    // per-wave v^T [hd][t]

  const int tid  = threadIdx.x;
  const int lane = tid & 63;
  const int w    = tid >> 6;
  const int m16 = lane & 15, q16 = lane >> 4;   // 16x16 MFMA coords
  const int m32 = lane & 31, h32 = lane >> 5;   // 32x32 MFMA coords

  // XCD swizzle: blockIdx%8 = XCD; contiguous 432-window chunk per XCD for L2 reuse
  const int blk  = blockIdx.x;                      // 3456 = 8 * 432
  const int g    = (blk & 7) * 432 + (blk >> 3);
  const int b    = g / NWIN;
  const int win  = g - b * NWIN;
  const int id   = win / 144;
  const int ihw  = win - id * 144;
  const int ih   = ihw / 12;
  const int iw   = ihw - ih * 12;

  short* sR  = sU;                                  // xs/ao: [64][SRS] bf16
  short* spw = sU + w * (32 * SVS);                 // per-wave P~ chunk [32][SVS]

  // prefetch the first QKV weight tile (h0, q) -> overlaps x staging
  short8 wcur[4];
  #pragma unroll
  for (int ks = 0; ks < 4; ++ks)
    wcur[ks] = *reinterpret_cast<const short8*>(
        wqkv_bf + ((2 * w) * 16 + m16) * 128 + ks * 32 + q16 * 8);

  // ---------- stage x window -> xs bf16 (2 ch packed per b32, conflict-free) ----------
  // All 8 scattered float4 loads issue up-front (one latency wall, not four).
  const float* xb = x + (size_t)b * (128 * SPD) + id * (4 * 2304) + ih * (4 * 48) + iw * 4;
  float4 xv[4][2];
  #pragma unroll
  for (int i = 0; i < 4; ++i) {
    int row = i * 4 + w;              // 0..15 = (dz, hy)
    const float* base = xb + (size_t)(lane * 2) * SPD + (row >> 2) * 2304 + (row & 3) * 48;
    xv[i][0] = *reinterpret_cast<const float4*>(base);
    xv[i][1] = *reinterpret_cast<const float4*>(base + SPD);
  }
  uint32_t* sRw = reinterpret_cast<uint32_t*>(sR);
  #pragma unroll
  for (int i = 0; i < 4; ++i) {
    int row = i * 4 + w;
    int cp  = lane;                   // channel pair
    int t = (row >> 2) * 16 + (row & 3) * 4;   // token = (wd*4+wh)*4+ww
    const float4 v0 = xv[i][0], v1 = xv[i][1];
    sRw[(t + 0) * (SRS / 2) + cp] = (uint32_t)(uint16_t)f2bf(v0.x) | ((uint32_t)(uint16_t)f2bf(v1.x) << 16);
    sRw[(t + 1) * (SRS / 2) + cp] = (uint32_t)(uint16_t)f2bf(v0.y) | ((uint32_t)(uint16_t)f2bf(v1.y) << 16);
    sRw[(t + 2) * (SRS / 2) + cp] = (uint32_t)(uint16_t)f2bf(v0.z) | ((uint32_t)(uint16_t)f2bf(v1.z) << 16);
    sRw[(t + 3) * (SRS / 2) + cp] = (uint32_t)(uint16_t)f2bf(v0.w) | ((uint32_t)(uint16_t)f2bf(v1.w) << 16);
  }
  __syncthreads();

  // preload all A-frags of X into registers (held through both heads' QKV)
  short8 afrag[4][4];
  #pragma unroll
  for (int mt = 0; mt < 4; ++mt)
    #pragma unroll
    for (int ks = 0; ks < 4; ++ks)
      afrag[mt][ks] = *reinterpret_cast<const short8*>(
          &sR[(mt * 16 + m16) * SRS + ks * 32 + q16 * 8]);
  __syncthreads();   // xs region free -> P~ chunks may overlay it

  f32x4 oacc0[4];    // head 0 normalized PV outputs
  f32x4 oacc1[4];    // head 1 normalized PV outputs

  const float scale = 0.08838834764831845f;   // 128^-0.5
  f32x16 z16;
  #pragma unroll
  for (int i = 0; i < 16; ++i) z16[i] = 0.0f;
  f32x4 z4;
  #pragma unroll
  for (int i = 0; i < 4; ++i) z4[i] = 0.0f;
  short8 ones8;                                // bf16 1.0 splat (B operand of rowsum MFMA)
  #pragma unroll
  for (int i = 0; i < 8; ++i) ones8[i] = (short)0x3F80;

  // ---- QKV for one head: 3 weight-pipelined tiles (q, k, v) ----
  auto do_qkv = [&](int h, bool pre) {
    #pragma unroll
    for (int which = 0; which < 3; ++which) {
      short8 wnext[4];
      const bool have_next = (which < 2) || pre;
      if (have_next) {
        const int net = (which < 2) ? ((which + 1) * 8 + h)  // next tile this head
                                    : (h + 1);               // q-tile of next head
        #pragma unroll
        for (int ks = 0; ks < 4; ++ks)
          wnext[ks] = *reinterpret_cast<const short8*>(
              wqkv_bf + (net * 16 + m16) * 128 + ks * 32 + q16 * 8);
      }
      f32x4 acc[4];
      #pragma unroll
      for (int mt = 0; mt < 4; ++mt)
        #pragma unroll
        for (int r = 0; r < 4; ++r) acc[mt][r] = 0.0f;
      #pragma unroll
      for (int ks = 0; ks < 4; ++ks)
        #pragma unroll
        for (int mt = 0; mt < 4; ++mt)
          acc[mt] = __builtin_amdgcn_mfma_f32_16x16x32_bf16(afrag[mt][ks], wcur[ks], acc[mt], 0, 0, 0);

      if (which == 0) {
        #pragma unroll
        for (int mt = 0; mt < 4; ++mt)
          #pragma unroll
          for (int r = 0; r < 4; ++r)
            sq[w][(mt * 16 + q16 * 4 + r) * SQS + m16] = f2bf(acc[mt][r]);
      } else if (which == 1) {
        #pragma unroll
        for (int mt = 0; mt < 4; ++mt)
          #pragma unroll
          for (int r = 0; r < 4; ++r)
            sk[w][(mt * 16 + q16 * 4 + r) * SQS + m16] = f2bf(acc[mt][r]);
      } else {
        #pragma unroll
        for (int mt = 0; mt < 4; ++mt) {
          short4v pk;
          pk[0] = f2bf(acc[mt][0]); pk[1] = f2bf(acc[mt][1]);
          pk[2] = f2bf(acc[mt][2]); pk[3] = f2bf(acc[mt][3]);
          *reinterpret_cast<short4v*>(&sv[w][m16 * SVS + mt * 16 + q16 * 4]) = pk;  // v^T[hd][t]
        }
      }
      if (have_next) {
        #pragma unroll
        for (int ks = 0; ks < 4; ++ks) wcur[ks] = wnext[ks];
      }
    }
  };

  // ---- attention for one head from hoisted register frags ----
  auto do_attn = [&](f32x4* oa, short8 qfA, short8 qfB, short8 kf0, short8 kf1,
                     short8 vf0, short8 vf1) {
    #pragma unroll
    for (int mt2 = 0; mt2 < 2; ++mt2) {
      short8 qf = mt2 ? qfB : qfA;
      f32x16 s0 = __builtin_amdgcn_mfma_f32_32x32x16_bf16(qf, kf0, z16, 0, 0, 0);
      f32x16 s1 = __builtin_amdgcn_mfma_f32_32x32x16_bf16(qf, kf1, z16, 0, 0, 0);
      CFENCE();   // WAR: prior P~/frag reads issue before these stores
      // store unnormalized P~ = exp(s*scale); no max subtraction (|s*scale| <~ 3)
      #pragma unroll
      for (int r = 0; r < 16; ++r) {
        int row = (r & 3) + 8 * (r >> 2) + 4 * h32;       // 32x32 C/D row map
        spw[row * SVS + m32]      = f2bf(__expf(s0[r] * scale));
        spw[row * SVS + 32 + m32] = f2bf(__expf(s1[r] * scale));
      }
      LFENCE();   // P~ stores drained before A-frag reads
      // PV: O[t][hd] = (P~[t][:] . V[:][hd]) / rowsum; rowsum via MFMA with B = ones
      #pragma unroll
      for (int sub = 0; sub < 2; ++sub) {
        short8 pf0 = *reinterpret_cast<const short8*>(&spw[(sub * 16 + m16) * SVS + q16 * 8]);
        short8 pf1 = *reinterpret_cast<const short8*>(&spw[(sub * 16 + m16) * SVS + 32 + q16 * 8]);
        int tile = mt2 * 2 + sub;
        f32x4 pv = __builtin_amdgcn_mfma_f32_16x16x32_bf16(pf0, vf0, z4, 0, 0, 0);
        pv       = __builtin_amdgcn_mfma_f32_16x16x32_bf16(pf1, vf1, pv, 0, 0, 0);
        f32x4 rs = __builtin_amdgcn_mfma_f32_16x16x32_bf16(pf0, ones8, z4, 0, 0, 0);
        rs       = __builtin_amdgcn_mfma_f32_16x16x32_bf16(pf1, ones8, rs, 0, 0, 0);
        #pragma unroll
        for (int r = 0; r < 4; ++r)
          oa[tile][r] = pv[r] * __builtin_amdgcn_rcpf(rs[r]);
      }
    }
  };

  // ===== head 0 QKV =====
  do_qkv(2 * w, /*pre=*/true);          // last iter prefetches h1's q-tile
  LFENCE();                             // h0 q/k/v stores drained

  // hoist ALL h0 operand frags -> sq/sk/sv dead for h0 (reads precede any
  // h1 overwrite: same-wave program order, in-order DS, same-array aliasing)
  short8 kf0 = *reinterpret_cast<const short8*>(&sk[w][(m32) * SQS + h32 * 8]);
  short8 kf1 = *reinterpret_cast<const short8*>(&sk[w][(32 + m32) * SQS + h32 * 8]);
  short8 vf0 = *reinterpret_cast<const short8*>(&sv[w][m16 * SVS + q16 * 8]);
  short8 vf1 = *reinterpret_cast<const short8*>(&sv[w][m16 * SVS + 32 + q16 * 8]);
  short8 qfA = *reinterpret_cast<const short8*>(&sq[w][(m32) * SQS + h32 * 8]);
  short8 qfB = *reinterpret_cast<const short8*>(&sq[w][(32 + m32) * SQS + h32 * 8]);

  // ===== head 1 QKV issued here: independent work that the scheduler can
  // interleave with head 0's attention below (fills exp/drain stall slots) =====
  do_qkv(2 * w + 1, /*pre=*/false);

  // ===== head 0 attention (register frags; P~ in spw region only) =====
  do_attn(oacc0, qfA, qfB, kf0, kf1, vf0, vf1);

  LFENCE();   // h1 q/k/v stores drained (usually already by attn's internal drains)

  // hoist h1 frags, then attention
  kf0 = *reinterpret_cast<const short8*>(&sk[w][(m32) * SQS + h32 * 8]);
  kf1 = *reinterpret_cast<const short8*>(&sk[w][(32 + m32) * SQS + h32 * 8]);
  vf0 = *reinterpret_cast<const short8*>(&sv[w][m16 * SVS + q16 * 8]);
  vf1 = *reinterpret_cast<const short8*>(&sv[w][m16 * SVS + 32 + q16 * 8]);
  qfA = *reinterpret_cast<const short8*>(&sq[w][(m32) * SQS + h32 * 8]);
  qfB = *reinterpret_cast<const short8*>(&sq[w][(32 + m32) * SQS + h32 * 8]);
  do_attn(oacc1, qfA, qfB, kf0, kf1, vf0, vf1);

  // hoist out-projection weight frags + bias (overlap the barriers below)
  short8 wob[2][4];
  #pragma unroll
  for (int ntl = 0; ntl < 2; ++ntl)
    #pragma unroll
    for (int ks = 0; ks < 4; ++ks)
      wob[ntl][ks] = *reinterpret_cast<const short8*>(
          wout_bf + ((2 * w + ntl) * 16 + m16) * 128 + ks * 32 + q16 * 8);
  float bias0 = bout[(2 * w) * 16 + m16];
  float bias1 = bout[(2 * w + 1) * 16 + m16];

  __syncthreads();   // all waves done with P~ chunks; reuse sR for ao

  // ---------- assemble ao[t][c] bf16 (already normalized) ----------
  #pragma unroll
  for (int hh = 0; hh < 2; ++hh) {
    int c0 = (2 * w + hh) * 16;
    const f32x4* oa = hh ? oacc1 : oacc0;
    #pragma unroll
    for (int mt = 0; mt < 4; ++mt)
      #pragma unroll
      for (int r = 0; r < 4; ++r)
        sR[(mt * 16 + q16 * 4 + r) * SRS + c0 + m16] = f2bf(oa[mt][r]);
  }
  __syncthreads();

  // ---------- out projection: OUT[t][co] = ao[t][:] . Wout[co][:] + bout ----------
  f32x4 outacc[4][2];
  #pragma unroll
  for (int i = 0; i < 4; ++i)
    #pragma unroll
    for (int j = 0; j < 2; ++j)
      #pragma unroll
      for (int r = 0; r < 4; ++r) outacc[i][j][r] = 0.0f;
  #pragma unroll
  for (int ks = 0; ks < 4; ++ks) {
    short8 af[4];
    #pragma unroll
    for (int mt = 0; mt < 4; ++mt)
      af[mt] = *reinterpret_cast<const short8*>(&sR[(mt * 16 + m16) * SRS + ks * 32 + q16 * 8]);
    #pragma unroll
    for (int ntl = 0; ntl < 2; ++ntl)
      #pragma unroll
      for (int mt = 0; mt < 4; ++mt)
        outacc[mt][ntl] = __builtin_amdgcn_mfma_f32_16x16x32_bf16(af[mt], wob[ntl][ks], outacc[mt][ntl], 0, 0, 0);
  }
  // epilogue: bias + coalesced float4 stores (window-order reshape => contiguous)
  #pragma unroll
  for (int ntl = 0; ntl < 2; ++ntl) {
    int co = (2 * w + ntl) * 16 + m16;
    float bias = ntl ? bias1 : bias0;
    float* obase = out + (size_t)(b * 128 + co) * SPD + win * 64;
    #pragma unroll
    for (int mt = 0; mt < 4; ++mt) {
      float4 vres;
      vres.x = outacc[mt][ntl][0] + bias;
      vres.y = outacc[mt][ntl][1] + bias;
      vres.z = outacc[mt][ntl][2] + bias;
      vres.w = outacc[mt][ntl][3] + bias;
      *reinterpret_cast<float4*>(obase + mt * 16 + q16 * 4) = vres;
    }
  }
}

extern "C" void kernel_launch(void* const* d_in, const int* in_sizes, int n_in,
                              void* d_out, int out_size, void* d_ws, size_t ws_size,
                              hipStream_t stream) {
  const float* x    = (const float*)d_in[0];
  const float* wqkv = (const float*)d_in[1];
  const float* wout = (const float*)d_in[2];
  const float* bout = (const float*)d_in[3];
  short* wq_bf = (short*)d_ws;                       //  98304 B
  short* wo_bf = (short*)((char*)d_ws + 98304);      //  32768 B
  cvt_weights_kernel<<<192, 256, 0, stream>>>(wqkv, wout, wq_bf, wo_bf);
  win_attn_kernel<<<2 * NWIN, 256, 0, stream>>>(x, wq_bf, wo_bf, bout, (float*)d_out);
}

// Round 12
// 268.316 us; speedup vs baseline: 1.0365x; 1.0365x over previous
//
#include <hip/hip_runtime.h>
#include <hip/hip_bf16.h>
#include <stdint.h>

#define NWIN 1728
#define SPD  110592   // 48*48*48

typedef __attribute__((ext_vector_type(8)))  short  short8;
typedef __attribute__((ext_vector_type(4)))  short  short4v;
typedef __attribute__((ext_vector_type(4)))  float  f32x4;
typedef __attribute__((ext_vector_type(16))) float  f32x16;

// LDS row strides (in shorts). All multiples of 8 (16-B row alignment for b128).
#define SRS 136   // x / ao tile rows
#define SQS 24    // sq/sk rows: 16-B aligned rows, writes 16 banks 2-way
#define SVS 72    // sv / P~ rows (36 words: b16 stores hit 32 banks 2-way = free)

// zero-cost compiler reorder fence (no instruction emitted)
#define CFENCE() asm volatile("" ::: "memory")
// hard LDS drain (proven R2 ordering for LDS RAW visibility)
#define LFENCE() asm volatile("s_waitcnt lgkmcnt(0)" ::: "memory")

// bf16 convert via compiler intrinsic: LLVM lowers fptrunc->bfloat to the HW
// packed convert (v_cvt_pk_bf16_f32) with RTNE — bit-identical to the old
// software RTNE path for all finite values, at ~1/4 the VALU instructions.
// (Hand-written cvt_pk asm is PERMANENTLY BANNED — R10 isolated it as the
//  R1/R3 NaN bug. This is the m240-sanctioned compiler path instead.)
__device__ __forceinline__ short f2bf(float f) {
  __hip_bfloat16 h = __float2bfloat16(f);
  return (short)__builtin_bit_cast(unsigned short, h);
}

// ---- one-time (per launch) fp32 -> bf16 weight conversion into workspace ----
__global__ void cvt_weights_kernel(const float* __restrict__ wqkv,
                                   const float* __restrict__ wout,
                                   short* __restrict__ wq_bf,
                                   short* __restrict__ wo_bf) {
  int i = blockIdx.x * 256 + threadIdx.x;   // grid = 192*256 = 49152 exactly
  wq_bf[i] = f2bf(wqkv[i]);
  if (i < 128 * 128) wo_bf[i] = f2bf(wout[i]);
}

// ---- fused: x -> qkv -> windowed attention -> out projection ----
// Structure = R9 exactly (harness-proven 135us kernel): batched staging loads,
// 6-tile QKV weight pipeline, norm fold into PV, (256,3), 52224B LDS.
// R11's head-overlap reverted (neutral). Single lever this round: f2bf via
// __float2bfloat16 (compiler-emitted packed convert, bit-identical rounding).
__global__ __launch_bounds__(256, 3)
void win_attn_kernel(const float* __restrict__ x,
                     const short* __restrict__ wqkv_bf,
                     const short* __restrict__ wout_bf,
                     const float* __restrict__ bout,
                     float* __restrict__ out) {
  // LDS: sU 18432 + sq 12288 + sk 12288 + sv 9216 = 52224 B (3 blocks/CU)
  __shared__ __align__(16) short sU[4 * 32 * SVS];   // xs (17408 used) / P~ / ao
  __shared__ __align__(16) short sq[4][64 * SQS];    // per-wave q  [t][hd]
  __shared__ __align__(16) short sk[4][64 * SQS];    // per-wave k  [t][hd]
  __shared__ __align__(16) short sv[4][16 * SVS];    // per-wave v^T [hd][t]

  const int tid  = threadIdx.x;
  const int lane = tid & 63;
  const int w    = tid >> 6;
  const int m16 = lane & 15, q16 = lane >> 4;   // 16x16 MFMA coords
  const int m32 = lane & 31, h32 = lane >> 5;   // 32x32 MFMA coords

  // XCD swizzle: blockIdx%8 = XCD; contiguous 432-window chunk per XCD for L2 reuse
  const int blk  = blockIdx.x;                      // 3456 = 8 * 432
  const int g    = (blk & 7) * 432 + (blk >> 3);
  const int b    = g / NWIN;
  const int win  = g - b * NWIN;
  const int id   = win / 144;
  const int ihw  = win - id * 144;
  const int ih   = ihw / 12;
  const int iw   = ihw - ih * 12;

  short* sR  = sU;                                  // xs/ao: [64][SRS] bf16
  short* spw = sU + w * (32 * SVS);                 // per-wave P~ chunk [32][SVS]

  // prefetch the first QKV weight tile (hh=0, which=0) -> overlaps x staging
  short8 wcur[4];
  #pragma unroll
  for (int ks = 0; ks < 4; ++ks)
    wcur[ks] = *reinterpret_cast<const short8*>(
        wqkv_bf + ((2 * w) * 16 + m16) * 128 + ks * 32 + q16 * 8);

  // ---------- stage x window -> xs bf16 (2 ch packed per b32, conflict-free) ----------
  // All 8 scattered float4 loads issue up-front (one latency wall, not four).
  const float* xb = x + (size_t)b * (128 * SPD) + id * (4 * 2304) + ih * (4 * 48) + iw * 4;
  float4 xv[4][2];
  #pragma unroll
  for (int i = 0; i < 4; ++i) {
    int row = i * 4 + w;              // 0..15 = (dz, hy)
    const float* base = xb + (size_t)(lane * 2) * SPD + (row >> 2) * 2304 + (row & 3) * 48;
    xv[i][0] = *reinterpret_cast<const float4*>(base);
    xv[i][1] = *reinterpret_cast<const float4*>(base + SPD);
  }
  uint32_t* sRw = reinterpret_cast<uint32_t*>(sR);
  #pragma unroll
  for (int i = 0; i < 4; ++i) {
    int row = i * 4 + w;
    int cp  = lane;                   // channel pair
    int t = (row >> 2) * 16 + (row & 3) * 4;   // token = (wd*4+wh)*4+ww
    const float4 v0 = xv[i][0], v1 = xv[i][1];
    sRw[(t + 0) * (SRS / 2) + cp] = (uint32_t)(uint16_t)f2bf(v0.x) | ((uint32_t)(uint16_t)f2bf(v1.x) << 16);
    sRw[(t + 1) * (SRS / 2) + cp] = (uint32_t)(uint16_t)f2bf(v0.y) | ((uint32_t)(uint16_t)f2bf(v1.y) << 16);
    sRw[(t + 2) * (SRS / 2) + cp] = (uint32_t)(uint16_t)f2bf(v0.z) | ((uint32_t)(uint16_t)f2bf(v1.z) << 16);
    sRw[(t + 3) * (SRS / 2) + cp] = (uint32_t)(uint16_t)f2bf(v0.w) | ((uint32_t)(uint16_t)f2bf(v1.w) << 16);
  }
  __syncthreads();

  // preload all A-frags of X into registers (held across both heads)
  short8 afrag[4][4];
  #pragma unroll
  for (int mt = 0; mt < 4; ++mt)
    #pragma unroll
    for (int ks = 0; ks < 4; ++ks)
      afrag[mt][ks] = *reinterpret_cast<const short8*>(
          &sR[(mt * 16 + m16) * SRS + ks * 32 + q16 * 8]);
  __syncthreads();   // xs region free -> P~ chunks may overlay it

  f32x4 oacc[2][4];  // [hh][tile] normalized PV outputs (written once in PV)

  const float scale = 0.08838834764831845f;   // 128^-0.5
  f32x16 z16;
  #pragma unroll
  for (int i = 0; i < 16; ++i) z16[i] = 0.0f;
  f32x4 z4;
  #pragma unroll
  for (int i = 0; i < 4; ++i) z4[i] = 0.0f;
  short8 ones8;                                // bf16 1.0 splat (B operand of rowsum MFMA)
  #pragma unroll
  for (int i = 0; i < 8; ++i) ones8[i] = (short)0x3F80;

  #pragma unroll
  for (int hh = 0; hh < 2; ++hh) {
    const int h = 2 * w + hh;

    // ---------- QKV for head h: e-tiles h (q), 8+h (k), 16+h (v) ----------
    // Pipelined: while tile j's MFMAs run, tile j+1's loads are in flight.
    // Tile sequence: q(h), k(8+h), v(16+h), then [hh=0 only] q(2w+1) across attn.
    #pragma unroll
    for (int which = 0; which < 3; ++which) {
      short8 wnext[4];
      const bool have_next = !(hh == 1 && which == 2);
      if (have_next) {
        const int net = (which < 2) ? ((which + 1) * 8 + h)   // next tile this head
                                    : (2 * w + 1);            // q-tile of head hh=1
        #pragma unroll
        for (int ks = 0; ks < 4; ++ks)
          wnext[ks] = *reinterpret_cast<const short8*>(
              wqkv_bf + (net * 16 + m16) * 128 + ks * 32 + q16 * 8);
      }
      f32x4 acc[4];
      #pragma unroll
      for (int mt = 0; mt < 4; ++mt)
        #pragma unroll
        for (int r = 0; r < 4; ++r) acc[mt][r] = 0.0f;
      #pragma unroll
      for (int ks = 0; ks < 4; ++ks)
        #pragma unroll
        for (int mt = 0; mt < 4; ++mt)
          acc[mt] = __builtin_amdgcn_mfma_f32_16x16x32_bf16(afrag[mt][ks], wcur[ks], acc[mt], 0, 0, 0);

      if (which == 0) {
        #pragma unroll
        for (int mt = 0; mt < 4; ++mt)
          #pragma unroll
          for (int r = 0; r < 4; ++r)
            sq[w][(mt * 16 + q16 * 4 + r) * SQS + m16] = f2bf(acc[mt][r]);
      } else if (which == 1) {
        #pragma unroll
        for (int mt = 0; mt < 4; ++mt)
          #pragma unroll
          for (int r = 0; r < 4; ++r)
            sk[w][(mt * 16 + q16 * 4 + r) * SQS + m16] = f2bf(acc[mt][r]);
      } else {
        #pragma unroll
        for (int mt = 0; mt < 4; ++mt) {
          short4v pk;
          pk[0] = f2bf(acc[mt][0]); pk[1] = f2bf(acc[mt][1]);
          pk[2] = f2bf(acc[mt][2]); pk[3] = f2bf(acc[mt][3]);
          *reinterpret_cast<short4v*>(&sv[w][m16 * SVS + mt * 16 + q16 * 4]) = pk;  // v^T[hd][t]
        }
      }
      if (have_next) {
        #pragma unroll
        for (int ks = 0; ks < 4; ++ks) wcur[ks] = wnext[ks];
      }
    }
    LFENCE();   // sq/sk/sv writes drained (also orders vs previous hh's P~/V reads)

    // ---------- attention for head h (wave-local) ----------
    short8 kf0 = *reinterpret_cast<const short8*>(&sk[w][(m32) * SQS + h32 * 8]);
    short8 kf1 = *reinterpret_cast<const short8*>(&sk[w][(32 + m32) * SQS + h32 * 8]);
    short8 vf0 = *reinterpret_cast<const short8*>(&sv[w][m16 * SVS + q16 * 8]);
    short8 vf1 = *reinterpret_cast<const short8*>(&sv[w][m16 * SVS + 32 + q16 * 8]);
    #pragma unroll
    for (int mt2 = 0; mt2 < 2; ++mt2) {
      short8 qf = *reinterpret_cast<const short8*>(&sq[w][(mt2 * 32 + m32) * SQS + h32 * 8]);
      f32x16 s0 = __builtin_amdgcn_mfma_f32_32x32x16_bf16(qf, kf0, z16, 0, 0, 0);
      f32x16 s1 = __builtin_amdgcn_mfma_f32_32x32x16_bf16(qf, kf1, z16, 0, 0, 0);
      CFENCE();   // WAR: previous chunk's P~ reads issue before these stores
      // store unnormalized P~ = exp(s*scale); no max subtraction (|s*scale| <~ 3)
      #pragma unroll
      for (int r = 0; r < 16; ++r) {
        int row = (r & 3) + 8 * (r >> 2) + 4 * h32;       // 32x32 C/D row map
        spw[row * SVS + m32]      = f2bf(__expf(s0[r] * scale));
        spw[row * SVS + 32 + m32] = f2bf(__expf(s1[r] * scale));
      }
      LFENCE();   // P~ stores drained before A-frag reads
      // PV: O[t][hd] = (P~[t][:] . V[:][hd]) / rowsum; rowsum via MFMA with B = ones.
      // Normalization folded (tile complete after pf0+pf1) -> no inv[] accumulators.
      #pragma unroll
      for (int sub = 0; sub < 2; ++sub) {
        short8 pf0 = *reinterpret_cast<const short8*>(&spw[(sub * 16 + m16) * SVS + q16 * 8]);
        short8 pf1 = *reinterpret_cast<const short8*>(&spw[(sub * 16 + m16) * SVS + 32 + q16 * 8]);
        int tile = mt2 * 2 + sub;
        f32x4 pv = __builtin_amdgcn_mfma_f32_16x16x32_bf16(pf0, vf0, z4, 0, 0, 0);
        pv       = __builtin_amdgcn_mfma_f32_16x16x32_bf16(pf1, vf1, pv, 0, 0, 0);
        f32x4 rs = __builtin_amdgcn_mfma_f32_16x16x32_bf16(pf0, ones8, z4, 0, 0, 0);
        rs       = __builtin_amdgcn_mfma_f32_16x16x32_bf16(pf1, ones8, rs, 0, 0, 0);
        #pragma unroll
        for (int r = 0; r < 4; ++r)
          oacc[hh][tile][r] = pv[r] * __builtin_amdgcn_rcpf(rs[r]);
      }
    }
  }

  // hoist out-projection weight frags + bias (overlap the barriers below)
  short8 wob[2][4];
  #pragma unroll
  for (int ntl = 0; ntl < 2; ++ntl)
    #pragma unroll
    for (int ks = 0; ks < 4; ++ks)
      wob[ntl][ks] = *reinterpret_cast<const short8*>(
          wout_bf + ((2 * w + ntl) * 16 + m16) * 128 + ks * 32 + q16 * 8);
  float bias0 = bout[(2 * w) * 16 + m16];
  float bias1 = bout[(2 * w + 1) * 16 + m16];

  __syncthreads();   // all waves done with P~ chunks; reuse sR for ao

  // ---------- assemble ao[t][c] bf16 (already normalized) ----------
  #pragma unroll
  for (int hh = 0; hh < 2; ++hh) {
    int c0 = (2 * w + hh) * 16;
    #pragma unroll
    for (int mt = 0; mt < 4; ++mt)
      #pragma unroll
      for (int r = 0; r < 4; ++r)
        sR[(mt * 16 + q16 * 4 + r) * SRS + c0 + m16] = f2bf(oacc[hh][mt][r]);
  }
  __syncthreads();

  // ---------- out projection: OUT[t][co] = ao[t][:] . Wout[co][:] + bout ----------
  f32x4 outacc[4][2];
  #pragma unroll
  for (int i = 0; i < 4; ++i)
    #pragma unroll
    for (int j = 0; j < 2; ++j)
      #pragma unroll
      for (int r = 0; r < 4; ++r) outacc[i][j][r] = 0.0f;
  #pragma unroll
  for (int ks = 0; ks < 4; ++ks) {
    short8 af[4];
    #pragma unroll
    for (int mt = 0; mt < 4; ++mt)
      af[mt] = *reinterpret_cast<const short8*>(&sR[(mt * 16 + m16) * SRS + ks * 32 + q16 * 8]);
    #pragma unroll
    for (int ntl = 0; ntl < 2; ++ntl)
      #pragma unroll
      for (int mt = 0; mt < 4; ++mt)
        outacc[mt][ntl] = __builtin_amdgcn_mfma_f32_16x16x32_bf16(af[mt], wob[ntl][ks], outacc[mt][ntl], 0, 0, 0);
  }
  // epilogue: bias + coalesced float4 stores (window-order reshape => contiguous)
  #pragma unroll
  for (int ntl = 0; ntl < 2; ++ntl) {
    int co = (2 * w + ntl) * 16 + m16;
    float bias = ntl ? bias1 : bias0;
    float* obase = out + (size_t)(b * 128 + co) * SPD + win * 64;
    #pragma unroll
    for (int mt = 0; mt < 4; ++mt) {
      float4 vres;
      vres.x = outacc[mt][ntl][0] + bias;
      vres.y = outacc[mt][ntl][1] + bias;
      vres.z = outacc[mt][ntl][2] + bias;
      vres.w = outacc[mt][ntl][3] + bias;
      *reinterpret_cast<float4*>(obase + mt * 16 + q16 * 4) = vres;
    }
  }
}

extern "C" void kernel_launch(void* const* d_in, const int* in_sizes, int n_in,
                              void* d_out, int out_size, void* d_ws, size_t ws_size,
                              hipStream_t stream) {
  const float* x    = (const float*)d_in[0];
  const float* wqkv = (const float*)d_in[1];
  const float* wout = (const float*)d_in[2];
  const float* bout = (const float*)d_in[3];
  short* wq_bf = (short*)d_ws;                       //  98304 B
  short* wo_bf = (short*)((char*)d_ws + 98304);      //  32768 B
  cvt_weights_kernel<<<192, 256, 0, stream>>>(wqkv, wout, wq_bf, wo_bf);
  win_attn_kernel<<<2 * NWIN, 256, 0, stream>>>(x, wq_bf, wo_bf, bout, (float*)d_out);
}

// Round 13
// 262.950 us; speedup vs baseline: 1.0576x; 1.0204x over previous
//
#include <hip/hip_runtime.h>
#include <hip/hip_bf16.h>
#include <stdint.h>

#define NWIN 1728
#define SPD  110592   // 48*48*48

typedef __attribute__((ext_vector_type(8)))  short  short8;
typedef __attribute__((ext_vector_type(4)))  short  short4v;
typedef __attribute__((ext_vector_type(4)))  float  f32x4;
typedef __attribute__((ext_vector_type(16))) float  f32x16;

// LDS row strides (in shorts). All multiples of 8 (16-B row alignment for b128).
#define SRS 136   // x / ao tile rows
#define SQS 24    // sq/sk rows: 16-B aligned rows, writes 16 banks 2-way
#define SVS 72    // sv / P~ rows (36 words: b16 stores hit 32 banks 2-way = free)

// zero-cost compiler reorder fence (no instruction emitted)
#define CFENCE() asm volatile("" ::: "memory")
// hard LDS drain (proven R2 ordering for LDS RAW visibility)
#define LFENCE() asm volatile("s_waitcnt lgkmcnt(0)" ::: "memory")

// bf16 convert via compiler intrinsic (R12-proven: bit-identical RTNE, ~1/4 the
// VALU of software emulation). Hand-written cvt_pk asm remains BANNED (R10 NaN).
__device__ __forceinline__ short f2bf(float f) {
  __hip_bfloat16 h = __float2bfloat16(f);
  return (short)__builtin_bit_cast(unsigned short, h);
}

// ---- one-time (per launch) fp32 -> bf16 weight conversion into workspace ----
__global__ void cvt_weights_kernel(const float* __restrict__ wqkv,
                                   const float* __restrict__ wout,
                                   short* __restrict__ wq_bf,
                                   short* __restrict__ wo_bf) {
  int i = blockIdx.x * 256 + threadIdx.x;   // grid = 192*256 = 49152 exactly
  wq_bf[i] = f2bf(wqkv[i]);
  if (i < 128 * 128) wo_bf[i] = f2bf(wout[i]);
}

// ---- fused: x -> qkv -> windowed attention -> out projection ----
// Base = R12 (harness-proven 131us). Single lever this round, numerics-identical:
// software-pipeline the two attention chunks per head — all 4 QK 32x32 MFMAs
// issue up-front (4-deep pipe), chunk-1's scores stay in registers (+32 VGPR,
// budget is 170 at our LDS-limited 3 waves/SIMD) so its exp chain overlaps
// chunk-0's store-drain + PV latency. Same stores, same rounding, same per-chunk
// LDS op order (WAR/RAW structure unchanged).
__global__ __launch_bounds__(256, 3)
void win_attn_kernel(const float* __restrict__ x,
                     const short* __restrict__ wqkv_bf,
                     const short* __restrict__ wout_bf,
                     const float* __restrict__ bout,
                     float* __restrict__ out) {
  // LDS: sU 18432 + sq 12288 + sk 12288 + sv 9216 = 52224 B (3 blocks/CU)
  __shared__ __align__(16) short sU[4 * 32 * SVS];   // xs (17408 used) / P~ / ao
  __shared__ __align__(16) short sq[4][64 * SQS];    // per-wave q  [t][hd]
  __shared__ __align__(16) short sk[4][64 * SQS];    // per-wave k  [t][hd]
  __shared__ __align__(16) short sv[4][16 * SVS];    // per-wave v^T [hd][t]

  const int tid  = threadIdx.x;
  const int lane = tid & 63;
  const int w    = tid >> 6;
  const int m16 = lane & 15, q16 = lane >> 4;   // 16x16 MFMA coords
  const int m32 = lane & 31, h32 = lane >> 5;   // 32x32 MFMA coords

  // XCD swizzle: blockIdx%8 = XCD; contiguous 432-window chunk per XCD for L2 reuse
  const int blk  = blockIdx.x;                      // 3456 = 8 * 432
  const int g    = (blk & 7) * 432 + (blk >> 3);
  const int b    = g / NWIN;
  const int win  = g - b * NWIN;
  const int id   = win / 144;
  const int ihw  = win - id * 144;
  const int ih   = ihw / 12;
  const int iw   = ihw - ih * 12;

  short* sR  = sU;                                  // xs/ao: [64][SRS] bf16
  short* spw = sU + w * (32 * SVS);                 // per-wave P~ chunk [32][SVS]

  // prefetch the first QKV weight tile (hh=0, which=0) -> overlaps x staging
  short8 wcur[4];
  #pragma unroll
  for (int ks = 0; ks < 4; ++ks)
    wcur[ks] = *reinterpret_cast<const short8*>(
        wqkv_bf + ((2 * w) * 16 + m16) * 128 + ks * 32 + q16 * 8);

  // ---------- stage x window -> xs bf16 (2 ch packed per b32, conflict-free) ----------
  // All 8 scattered float4 loads issue up-front (one latency wall, not four).
  const float* xb = x + (size_t)b * (128 * SPD) + id * (4 * 2304) + ih * (4 * 48) + iw * 4;
  float4 xv[4][2];
  #pragma unroll
  for (int i = 0; i < 4; ++i) {
    int row = i * 4 + w;              // 0..15 = (dz, hy)
    const float* base = xb + (size_t)(lane * 2) * SPD + (row >> 2) * 2304 + (row & 3) * 48;
    xv[i][0] = *reinterpret_cast<const float4*>(base);
    xv[i][1] = *reinterpret_cast<const float4*>(base + SPD);
  }
  uint32_t* sRw = reinterpret_cast<uint32_t*>(sR);
  #pragma unroll
  for (int i = 0; i < 4; ++i) {
    int row = i * 4 + w;
    int cp  = lane;                   // channel pair
    int t = (row >> 2) * 16 + (row & 3) * 4;   // token = (wd*4+wh)*4+ww
    const float4 v0 = xv[i][0], v1 = xv[i][1];
    sRw[(t + 0) * (SRS / 2) + cp] = (uint32_t)(uint16_t)f2bf(v0.x) | ((uint32_t)(uint16_t)f2bf(v1.x) << 16);
    sRw[(t + 1) * (SRS / 2) + cp] = (uint32_t)(uint16_t)f2bf(v0.y) | ((uint32_t)(uint16_t)f2bf(v1.y) << 16);
    sRw[(t + 2) * (SRS / 2) + cp] = (uint32_t)(uint16_t)f2bf(v0.z) | ((uint32_t)(uint16_t)f2bf(v1.z) << 16);
    sRw[(t + 3) * (SRS / 2) + cp] = (uint32_t)(uint16_t)f2bf(v0.w) | ((uint32_t)(uint16_t)f2bf(v1.w) << 16);
  }
  __syncthreads();

  // preload all A-frags of X into registers (held across both heads)
  short8 afrag[4][4];
  #pragma unroll
  for (int mt = 0; mt < 4; ++mt)
    #pragma unroll
    for (int ks = 0; ks < 4; ++ks)
      afrag[mt][ks] = *reinterpret_cast<const short8*>(
          &sR[(mt * 16 + m16) * SRS + ks * 32 + q16 * 8]);
  __syncthreads();   // xs region free -> P~ chunks may overlay it

  f32x4 oacc[2][4];  // [hh][tile] normalized PV outputs (written once in PV)

  const float scale = 0.08838834764831845f;   // 128^-0.5
  f32x16 z16;
  #pragma unroll
  for (int i = 0; i < 16; ++i) z16[i] = 0.0f;
  f32x4 z4;
  #pragma unroll
  for (int i = 0; i < 4; ++i) z4[i] = 0.0f;
  short8 ones8;                                // bf16 1.0 splat (B operand of rowsum MFMA)
  #pragma unroll
  for (int i = 0; i < 8; ++i) ones8[i] = (short)0x3F80;

  #pragma unroll
  for (int hh = 0; hh < 2; ++hh) {
    const int h = 2 * w + hh;

    // ---------- QKV for head h: e-tiles h (q), 8+h (k), 16+h (v) ----------
    // Pipelined: while tile j's MFMAs run, tile j+1's loads are in flight.
    #pragma unroll
    for (int which = 0; which < 3; ++which) {
      short8 wnext[4];
      const bool have_next = !(hh == 1 && which == 2);
      if (have_next) {
        const int net = (which < 2) ? ((which + 1) * 8 + h)   // next tile this head
                                    : (2 * w + 1);            // q-tile of head hh=1
        #pragma unroll
        for (int ks = 0; ks < 4; ++ks)
          wnext[ks] = *reinterpret_cast<const short8*>(
              wqkv_bf + (net * 16 + m16) * 128 + ks * 32 + q16 * 8);
      }
      f32x4 acc[4];
      #pragma unroll
      for (int mt = 0; mt < 4; ++mt)
        #pragma unroll
        for (int r = 0; r < 4; ++r) acc[mt][r] = 0.0f;
      #pragma unroll
      for (int ks = 0; ks < 4; ++ks)
        #pragma unroll
        for (int mt = 0; mt < 4; ++mt)
          acc[mt] = __builtin_amdgcn_mfma_f32_16x16x32_bf16(afrag[mt][ks], wcur[ks], acc[mt], 0, 0, 0);

      if (which == 0) {
        #pragma unroll
        for (int mt = 0; mt < 4; ++mt)
          #pragma unroll
          for (int r = 0; r < 4; ++r)
            sq[w][(mt * 16 + q16 * 4 + r) * SQS + m16] = f2bf(acc[mt][r]);
      } else if (which == 1) {
        #pragma unroll
        for (int mt = 0; mt < 4; ++mt)
          #pragma unroll
          for (int r = 0; r < 4; ++r)
            sk[w][(mt * 16 + q16 * 4 + r) * SQS + m16] = f2bf(acc[mt][r]);
      } else {
        #pragma unroll
        for (int mt = 0; mt < 4; ++mt) {
          short4v pk;
          pk[0] = f2bf(acc[mt][0]); pk[1] = f2bf(acc[mt][1]);
          pk[2] = f2bf(acc[mt][2]); pk[3] = f2bf(acc[mt][3]);
          *reinterpret_cast<short4v*>(&sv[w][m16 * SVS + mt * 16 + q16 * 4]) = pk;  // v^T[hd][t]
        }
      }
      if (have_next) {
        #pragma unroll
        for (int ks = 0; ks < 4; ++ks) wcur[ks] = wnext[ks];
      }
    }
    LFENCE();   // sq/sk/sv writes drained (also orders vs previous hh's P~/V reads)

    // ---------- attention for head h (wave-local), 2-chunk software pipeline ----------
    short8 kf0 = *reinterpret_cast<const short8*>(&sk[w][(m32) * SQS + h32 * 8]);
    short8 kf1 = *reinterpret_cast<const short8*>(&sk[w][(32 + m32) * SQS + h32 * 8]);
    short8 vf0 = *reinterpret_cast<const short8*>(&sv[w][m16 * SVS + q16 * 8]);
    short8 vf1 = *reinterpret_cast<const short8*>(&sv[w][m16 * SVS + 32 + q16 * 8]);
    short8 qfA = *reinterpret_cast<const short8*>(&sq[w][(m32) * SQS + h32 * 8]);
    short8 qfB = *reinterpret_cast<const short8*>(&sq[w][(32 + m32) * SQS + h32 * 8]);

    // all 4 QK MFMAs up-front: 4-deep matrix pipe, first pair's latency hidden
    f32x16 s0a = __builtin_amdgcn_mfma_f32_32x32x16_bf16(qfA, kf0, z16, 0, 0, 0);
    f32x16 s1a = __builtin_amdgcn_mfma_f32_32x32x16_bf16(qfA, kf1, z16, 0, 0, 0);
    f32x16 s0b = __builtin_amdgcn_mfma_f32_32x32x16_bf16(qfB, kf0, z16, 0, 0, 0);
    f32x16 s1b = __builtin_amdgcn_mfma_f32_32x32x16_bf16(qfB, kf1, z16, 0, 0, 0);
    CFENCE();   // WAR: previous head's P~ reads / frag hoists issue before stores

    // ---- chunk 0: exp + store P~ ----
    #pragma unroll
    for (int r = 0; r < 16; ++r) {
      int row = (r & 3) + 8 * (r >> 2) + 4 * h32;       // 32x32 C/D row map
      spw[row * SVS + m32]      = f2bf(__expf(s0a[r] * scale));
      spw[row * SVS + 32 + m32] = f2bf(__expf(s1a[r] * scale));
    }
    LFENCE();   // chunk-0 P~ stores drained before PV reads
    // ---- PV chunk 0 (chunk-1's exp chain is register-only and can schedule
    //      into these MFMAs' latency shadows) ----
    #pragma unroll
    for (int sub = 0; sub < 2; ++sub) {
      short8 pf0 = *reinterpret_cast<const short8*>(&spw[(sub * 16 + m16) * SVS + q16 * 8]);
      short8 pf1 = *reinterpret_cast<const short8*>(&spw[(sub * 16 + m16) * SVS + 32 + q16 * 8]);
      f32x4 pv = __builtin_amdgcn_mfma_f32_16x16x32_bf16(pf0, vf0, z4, 0, 0, 0);
      pv       = __builtin_amdgcn_mfma_f32_16x16x32_bf16(pf1, vf1, pv, 0, 0, 0);
      f32x4 rs = __builtin_amdgcn_mfma_f32_16x16x32_bf16(pf0, ones8, z4, 0, 0, 0);
      rs       = __builtin_amdgcn_mfma_f32_16x16x32_bf16(pf1, ones8, rs, 0, 0, 0);
      #pragma unroll
      for (int r = 0; r < 4; ++r)
        oacc[hh][sub][r] = pv[r] * __builtin_amdgcn_rcpf(rs[r]);
    }
    CFENCE();   // chunk-0 P~ reads issue before chunk-1 stores (in-order DS)

    // ---- chunk 1: exp + store P~ ----
    #pragma unroll
    for (int r = 0; r < 16; ++r) {
      int row = (r & 3) + 8 * (r >> 2) + 4 * h32;
      spw[row * SVS + m32]      = f2bf(__expf(s0b[r] * scale));
      spw[row * SVS + 32 + m32] = f2bf(__expf(s1b[r] * scale));
    }
    LFENCE();   // chunk-1 P~ stores drained before PV reads
    #pragma unroll
    for (int sub = 0; sub < 2; ++sub) {
      short8 pf0 = *reinterpret_cast<const short8*>(&spw[(sub * 16 + m16) * SVS + q16 * 8]);
      short8 pf1 = *reinterpret_cast<const short8*>(&spw[(sub * 16 + m16) * SVS + 32 + q16 * 8]);
      f32x4 pv = __builtin_amdgcn_mfma_f32_16x16x32_bf16(pf0, vf0, z4, 0, 0, 0);
      pv       = __builtin_amdgcn_mfma_f32_16x16x32_bf16(pf1, vf1, pv, 0, 0, 0);
      f32x4 rs = __builtin_amdgcn_mfma_f32_16x16x32_bf16(pf0, ones8, z4, 0, 0, 0);
      rs       = __builtin_amdgcn_mfma_f32_16x16x32_bf16(pf1, ones8, rs, 0, 0, 0);
      #pragma unroll
      for (int r = 0; r < 4; ++r)
        oacc[hh][2 + sub][r] = pv[r] * __builtin_amdgcn_rcpf(rs[r]);
    }
    CFENCE();   // pin hh boundary: next head's q/k/v stores stay below these reads
  }

  // hoist out-projection weight frags + bias (overlap the barriers below)
  short8 wob[2][4];
  #pragma unroll
  for (int ntl = 0; ntl < 2; ++ntl)
    #pragma unroll
    for (int ks = 0; ks < 4; ++ks)
      wob[ntl][ks] = *reinterpret_cast<const short8*>(
          wout_bf + ((2 * w + ntl) * 16 + m16) * 128 + ks * 32 + q16 * 8);
  float bias0 = bout[(2 * w) * 16 + m16];
  float bias1 = bout[(2 * w + 1) * 16 + m16];

  __syncthreads();   // all waves done with P~ chunks; reuse sR for ao

  // ---------- assemble ao[t][c] bf16 (already normalized) ----------
  #pragma unroll
  for (int hh = 0; hh < 2; ++hh) {
    int c0 = (2 * w + hh) * 16;
    #pragma unroll
    for (int mt = 0; mt < 4; ++mt)
      #pragma unroll
      for (int r = 0; r < 4; ++r)
        sR[(mt * 16 + q16 * 4 + r) * SRS + c0 + m16] = f2bf(oacc[hh][mt][r]);
  }
  __syncthreads();

  // ---------- out projection: OUT[t][co] = ao[t][:] . Wout[co][:] + bout ----------
  f32x4 outacc[4][2];
  #pragma unroll
  for (int i = 0; i < 4; ++i)
    #pragma unroll
    for (int j = 0; j < 2; ++j)
      #pragma unroll
      for (int r = 0; r < 4; ++r) outacc[i][j][r] = 0.0f;
  #pragma unroll
  for (int ks = 0; ks < 4; ++ks) {
    short8 af[4];
    #pragma unroll
    for (int mt = 0; mt < 4; ++mt)
      af[mt] = *reinterpret_cast<const short8*>(&sR[(mt * 16 + m16) * SRS + ks * 32 + q16 * 8]);
    #pragma unroll
    for (int ntl = 0; ntl < 2; ++ntl)
      #pragma unroll
      for (int mt = 0; mt < 4; ++mt)
        outacc[mt][ntl] = __builtin_amdgcn_mfma_f32_16x16x32_bf16(af[mt], wob[ntl][ks], outacc[mt][ntl], 0, 0, 0);
  }
  // epilogue: bias + coalesced float4 stores (window-order reshape => contiguous)
  #pragma unroll
  for (int ntl = 0; ntl < 2; ++ntl) {
    int co = (2 * w + ntl) * 16 + m16;
    float bias = ntl ? bias1 : bias0;
    float* obase = out + (size_t)(b * 128 + co) * SPD + win * 64;
    #pragma unroll
    for (int mt = 0; mt < 4; ++mt) {
      float4 vres;
      vres.x = outacc[mt][ntl][0] + bias;
      vres.y = outacc[mt][ntl][1] + bias;
      vres.z = outacc[mt][ntl][2] + bias;
      vres.w = outacc[mt][ntl][3] + bias;
      *reinterpret_cast<float4*>(obase + mt * 16 + q16 * 4) = vres;
    }
  }
}

extern "C" void kernel_launch(void* const* d_in, const int* in_sizes, int n_in,
                              void* d_out, int out_size, void* d_ws, size_t ws_size,
                              hipStream_t stream) {
  const float* x    = (const float*)d_in[0];
  const float* wqkv = (const float*)d_in[1];
  const float* wout = (const float*)d_in[2];
  const float* bout = (const float*)d_in[3];
  short* wq_bf = (short*)d_ws;                       //  98304 B
  short* wo_bf = (short*)((char*)d_ws + 98304);      //  32768 B
  cvt_weights_kernel<<<192, 256, 0, stream>>>(wqkv, wout, wq_bf, wo_bf);
  win_attn_kernel<<<2 * NWIN, 256, 0, stream>>>(x, wq_bf, wo_bf, bout, (float*)d_out);
}